// Round 17
// baseline (124.663 us; speedup 1.0000x reference)
//
#include <hip/hip_runtime.h>

#define T_SEQ 1024
#define DM 512
#define DI 1024
#define NS 16
#define NC 32      // scan chunks
#define CL 32      // chunk length (NC*CL == T_SEQ)

typedef __attribute__((ext_vector_type(8))) short short8;
typedef __attribute__((ext_vector_type(4))) float f32x4;
typedef unsigned short u16;
typedef unsigned int u32;

__device__ inline float b2f(u16 u) {
    unsigned v = ((unsigned)u) << 16;
    return __builtin_bit_cast(float, v);
}
__device__ inline u16 f2b(float f) {
    unsigned u = __builtin_bit_cast(unsigned, f);
    u += 0x7fff + ((u >> 16) & 1);   // RNE
    return (u16)(u >> 16);
}

// async global -> LDS, 16B/lane: per-lane global src, wave-uniform LDS base (+lane*16 by HW)
__device__ inline void g2l16(const u16* g, const short* l) {
    __builtin_amdgcn_global_load_lds((const __attribute__((address_space(1))) u32*)g,
                                     (__attribute__((address_space(3))) u32*)l, 16, 0, 0);
}

template<int K> __device__ __forceinline__ void vmwait() {
    if constexpr (K == 0) asm volatile("s_waitcnt vmcnt(0)" ::: "memory");
    else if constexpr (K == 2) asm volatile("s_waitcnt vmcnt(2)" ::: "memory");
    else if constexpr (K == 3) asm volatile("s_waitcnt vmcnt(3)" ::: "memory");
}

// ---------------- prep: cast weights + build wCat (1088x1024) + LayerNorm ----------------
// wCat rows: [0,1024)=W_dt, [1024,1040)=W_B, [1040,1056)=W_C, [1056,1088)=zeros
__global__ __launch_bounds__(256) void prep_k(const float* __restrict__ Win, const float* __restrict__ Wdt,
                       const float* __restrict__ Wout, const float* __restrict__ Wb,
                       const float* __restrict__ Wc,
                       u16* __restrict__ oWin, u16* __restrict__ wCat, u16* __restrict__ oWout,
                       const float* __restrict__ x, const float* __restrict__ g,
                       const float* __restrict__ be, u16* __restrict__ xn) {
    if (blockIdx.x < 2624) {
        int i = blockIdx.x * 256 + threadIdx.x;     // float4 index
        const float* s; u16* d; int off;
        if (i < 262144)      { s = Win;  d = oWin;  off = i; }
        else if (i < 524288) { s = Wdt;  d = wCat;  off = i - 262144; }
        else if (i < 655360) { s = Wout; d = oWout; off = i - 524288; }
        else if (i < 659456) { s = Wb;   d = wCat + 1048576; off = i - 655360; }
        else if (i < 663552) { s = Wc;   d = wCat + 1064960; off = i - 659456; }
        else {  // zero pad rows 1056..1087
            u16* dz = wCat + 1081344 + (i - 663552) * 4;
            dz[0] = 0; dz[1] = 0; dz[2] = 0; dz[3] = 0;
            return;
        }
        float4 v = ((const float4*)s)[off];
        d[off * 4 + 0] = f2b(v.x);
        d[off * 4 + 1] = f2b(v.y);
        d[off * 4 + 2] = f2b(v.z);
        d[off * 4 + 3] = f2b(v.w);
        return;
    }
    int row = blockIdx.x - 2624, tid = threadIdx.x;
    float2 v = ((const float2*)(x + row * DM))[tid];
    float s = v.x + v.y, q = v.x * v.x + v.y * v.y;
    #pragma unroll
    for (int m = 1; m < 64; m <<= 1) { s += __shfl_xor(s, m); q += __shfl_xor(q, m); }
    __shared__ float ss[4], qq[4];
    if ((tid & 63) == 0) { ss[tid >> 6] = s; qq[tid >> 6] = q; }
    __syncthreads();
    s = ss[0] + ss[1] + ss[2] + ss[3];
    q = qq[0] + qq[1] + qq[2] + qq[3];
    float mu = s / DM;
    float var = q / DM - mu * mu;
    float rs = rsqrtf(var + 1e-5f);
    int c = tid * 2;
    xn[row * DM + c]     = f2b((v.x - mu) * rs * g[c] + be[c]);
    xn[row * DM + c + 1] = f2b((v.y - mu) * rs * g[c + 1] + be[c + 1]);
}

// ---------------- gemm128: 128(M)x64(N) tile, BK=32, 4 waves (2x2 of 64x32) ----------------
// m97-style amortization: per phase per wave = 6 ds_read_b128 + 8 MFMA (0.75 reads/MFMA,
// vs 1.5 in the 64x64 core). Ring-3 LDS (18KB), depth-2 prefetch, counted vmcnt(3)
// (3 g2l16/thread/stage), ONE barrier per phase, setprio on MFMA. LINEAR LDS: BK=32 row
// stride = 64B -> 2-way bank aliasing = free (m136), no swizzle needed.
// EPI 0: bf16  EPI 4: cols<1024 softplus->bf16, 1024-1039->Bt f32, 1040-1055->Ct f32, drop rest
template<int NT, int EPI>
__global__ __launch_bounds__(256) void gemm128(int gx,
        const u16* __restrict__ A, int lda, const u16* __restrict__ Bw, int ldb,
        void* __restrict__ outp, int ldo, const float* __restrict__ extra,
        float* __restrict__ BtF, float* __restrict__ CtF) {
    __shared__ short a_sh[3 * 4096];        // 3 stages x 128x32
    __shared__ short b_sh[3 * 2048];        // 3 stages x 64x32
    int bx = blockIdx.x % gx, by = blockIdx.x / gx;
    int tid = threadIdx.x, w = tid >> 6, lane = tid & 63;
    int m0 = bx * 128, n0 = by * 64;
    int wr = (w >> 1) * 64, wc = (w & 1) * 32;
    int lr = lane & 15, kg = lane >> 4;     // kg = 16B k-chunk 0..3
    f32x4 acc[4][2] = {};
    const u16* Abase = A + (size_t)m0 * lda;
    const u16* Bbase = Bw + (size_t)n0 * ldb;
    int srow = w * 16 + (lane >> 2);        // 0..63
    int schunk = lane & 3;                  // 16B chunk within 64B row

    auto stage = [&](int buf, int kt) {
        int k0 = kt * 32;
        g2l16(Abase + (size_t)srow * lda + k0 + schunk * 8, a_sh + buf * 4096 + w * 512);
        g2l16(Abase + (size_t)(srow + 64) * lda + k0 + schunk * 8, a_sh + buf * 4096 + 2048 + w * 512);
        g2l16(Bbase + (size_t)srow * ldb + k0 + schunk * 8, b_sh + buf * 2048 + w * 512);
    };

    stage(0, 0);
    stage(1, 1);
    for (int t = 0; t < NT; ++t) {
        if (t + 1 < NT) vmwait<3>();        // tile t's 3 loads done; t+1's stay in flight
        else vmwait<0>();
        __builtin_amdgcn_s_barrier();       // tile t visible to all; buf[(t-1)%3] reads done
        if (t + 2 < NT) stage((t + 2) % 3, t + 2);
        const short* as = a_sh + (t % 3) * 4096;
        const short* bs = b_sh + (t % 3) * 2048;
        __builtin_amdgcn_s_setprio(1);
        short8 af[4], bfr[2];
        #pragma unroll
        for (int i = 0; i < 4; ++i)
            af[i] = *(const short8*)&as[(wr + i * 16 + lr) * 32 + kg * 8];
        #pragma unroll
        for (int j = 0; j < 2; ++j)
            bfr[j] = *(const short8*)&bs[(wc + j * 16 + lr) * 32 + kg * 8];
        #pragma unroll
        for (int i = 0; i < 4; ++i)
            #pragma unroll
            for (int j = 0; j < 2; ++j)
                acc[i][j] = __builtin_amdgcn_mfma_f32_16x16x32_bf16(af[i], bfr[j], acc[i][j], 0, 0, 0);
        __builtin_amdgcn_s_setprio(0);
    }

    int rb = (lane >> 4) * 4, cc = lane & 15;
    #pragma unroll
    for (int i = 0; i < 4; ++i) {
        #pragma unroll
        for (int j = 0; j < 2; ++j) {
            #pragma unroll
            for (int r = 0; r < 4; ++r) {
                int row = m0 + wr + i * 16 + rb + r;
                int col = n0 + wc + j * 16 + cc;
                float v = acc[i][j][r];
                if (EPI == 0) {
                    ((u16*)outp)[(size_t)row * ldo + col] = f2b(v);
                } else {   // EPI 4: dt | Bt | Ct | drop
                    if (col < 1024) {
                        float xx = v + extra[col];
                        float sp = (xx > 20.f) ? xx : log1pf(__expf(xx));
                        ((u16*)outp)[(size_t)row * ldo + col] = f2b(sp);
                    } else if (col < 1040) {
                        BtF[(size_t)row * NS + (col - 1024)] = v;
                    } else if (col < 1056) {
                        CtF[(size_t)row * NS + (col - 1040)] = v;
                    }
                }
            }
        }
    }
}

// ---------------- bf16 GEMM core: 64x64 tile, BK=64, 8 WAVES (512 thr) — r13 proven ----------------
template<int NT, int EPI>
__device__ __forceinline__ void gemm_core64(int bx, int by,
        const u16* __restrict__ A, int lda, const u16* __restrict__ Bw, int ldb,
        void* __restrict__ outp, int ldo, const float* __restrict__ extra) {
    __shared__ short a_sh[3 * 4096];        // 3 stages x 64x64
    __shared__ short b_sh[3 * 4096];
    int tid = threadIdx.x, w = tid >> 6, lane = tid & 63;
    int m0 = bx * 64, n0 = by * 64;
    int wr = (w >> 2) * 32, wc = (w & 3) * 16;
    int lr = lane & 15, kg = lane >> 4;
    f32x4 acc[2] = {};
    const u16* Abase = A + (size_t)m0 * lda;
    const u16* Bbase = Bw + (size_t)n0 * ldb;
    int lrow = lane >> 3;                   // 0..7
    int cl = lane & 7;                      // 16B chunk within 128B row
    int row1 = w * 8 + lrow;                // 0..63
    int sc = cl ^ (row1 & 7);               // pre-swizzled source chunk (involution)

    auto stage = [&](int buf, int kt) {
        int k0 = kt * 64;
        g2l16(Abase + (size_t)row1 * lda + k0 + sc * 8, a_sh + buf * 4096 + w * 512);
        g2l16(Bbase + (size_t)row1 * ldb + k0 + sc * 8, b_sh + buf * 4096 + w * 512);
    };

    stage(0, 0);
    stage(1, 1);
    for (int t = 0; t < NT; ++t) {
        if (t + 1 < NT) vmwait<2>();
        else vmwait<0>();
        __builtin_amdgcn_s_barrier();
        if (t + 2 < NT) stage((t + 2) % 3, t + 2);
        const short* as = a_sh + (t % 3) * 4096;
        const short* bs = b_sh + (t % 3) * 4096;
        int rsw = lr & 7;
        __builtin_amdgcn_s_setprio(1);
        #pragma unroll
        for (int kk = 0; kk < 2; ++kk) {
            short8 af[2], bfr;
            #pragma unroll
            for (int i = 0; i < 2; ++i) {
                int row = wr + i * 16 + lr;
                af[i] = *(const short8*)&as[row * 64 + ((kk * 4 + kg) ^ rsw) * 8];
            }
            {
                int row = wc + lr;
                bfr = *(const short8*)&bs[row * 64 + ((kk * 4 + kg) ^ rsw) * 8];
            }
            #pragma unroll
            for (int i = 0; i < 2; ++i)
                acc[i] = __builtin_amdgcn_mfma_f32_16x16x32_bf16(af[i], bfr, acc[i], 0, 0, 0);
        }
        __builtin_amdgcn_s_setprio(0);
    }

    int rb = (lane >> 4) * 4, cc = lane & 15;
    #pragma unroll
    for (int i = 0; i < 2; ++i) {
        #pragma unroll
        for (int r = 0; r < 4; ++r) {
            int row = m0 + wr + i * 16 + rb + r;
            int col = n0 + wc + cc;
            float v = acc[i][r];
            if (EPI == 3) {
                ((float*)outp)[(size_t)row * ldo + col] = v;
            }
        }
    }
}

// gemm2 split-K2: 512 blocks = 2 k-halves x (32 m x 8 n); f32 partials
__global__ __launch_bounds__(512) void gemm2_k(const u16* __restrict__ ym, const u16* __restrict__ Wout,
                                               float* __restrict__ p0, float* __restrict__ p1) {
    int bid = blockIdx.x;
    int ks = bid >> 8, rem = bid & 255;
    int bx = rem & 31, by = rem >> 5;
    float* p = ks ? p1 : p0;
    gemm_core64<8, 3>(bx, by, ym + ks * 512, DI, Wout + ks * 512, DI,
                      (void*)p, DM, nullptr);
}

// merge split-K partials + residual -> f32 out
__global__ __launch_bounds__(256) void merge_k(const float* __restrict__ p0, const float* __restrict__ p1,
                                               const float* __restrict__ x, float* __restrict__ out) {
    int i = blockIdx.x * 256 + threadIdx.x;   // float4 index, 262144 total
    float4 a = ((const float4*)p0)[i];
    float4 b = ((const float4*)p1)[i];
    float4 e = ((const float4*)x)[i];
    float4 o;
    o.x = a.x + b.x + e.x;
    o.y = a.y + b.y + e.y;
    o.z = a.z + b.z + e.z;
    o.w = a.w + b.w + e.w;
    ((float4*)out)[i] = o;
}

// ---------------- depthwise causal conv(k=4) + SiLU: 4 elems/thread, 2048 blocks ----------------
__global__ __launch_bounds__(256) void conv_k(const u16* __restrict__ xz, const float* __restrict__ w,
                                              const float* __restrict__ cb, u16* __restrict__ xf) {
    int base = (blockIdx.x * 256 + threadIdx.x) * 4;   // = (b*T + t)*DI + d0, d0 % 4 == 0
    int d0 = base & (DI - 1);
    int bt = base >> 10;
    int t = bt & (T_SEQ - 1);
    float4 cbv = *(const float4*)(cb + d0);
    float s0 = cbv.x, s1 = cbv.y, s2 = cbv.z, s3 = cbv.w;
    float4 w0 = *(const float4*)(w + (d0 + 0) * 4);
    float4 w1 = *(const float4*)(w + (d0 + 1) * 4);
    float4 w2 = *(const float4*)(w + (d0 + 2) * 4);
    float4 w3 = *(const float4*)(w + (d0 + 3) * 4);
    const float* pw0 = (const float*)&w0;
    const float* pw1 = (const float*)&w1;
    const float* pw2 = (const float*)&w2;
    const float* pw3 = (const float*)&w3;
    #pragma unroll
    for (int i = 0; i < 4; ++i) {
        int tt = t - 3 + i;
        if (tt >= 0) {
            ushort4 xv = *(const ushort4*)(xz + (size_t)(bt - 3 + i) * 2048 + d0);
            s0 += pw0[i] * b2f(xv.x);
            s1 += pw1[i] * b2f(xv.y);
            s2 += pw2[i] * b2f(xv.z);
            s3 += pw3[i] * b2f(xv.w);
        }
    }
    ushort4 o;
    o.x = f2b(s0 / (1.f + __expf(-s0)));
    o.y = f2b(s1 / (1.f + __expf(-s1)));
    o.z = f2b(s2 / (1.f + __expf(-s2)));
    o.w = f2b(s3 / (1.f + __expf(-s3)));
    *(ushort4*)(xf + base) = o;
}

// ---------------- chunked selective scan (CL=32, NC=32) ----------------
__global__ __launch_bounds__(256) void scanA(const u16* __restrict__ dt, const u16* __restrict__ xf,
                                             const float* __restrict__ Bt, const float* __restrict__ logA,
                                             float* __restrict__ Aprod, float* __restrict__ S) {
    int tid = threadIdx.x;
    int dblk = blockIdx.x & 3;          // DI/256
    int c = (blockIdx.x >> 2) & (NC - 1);
    int b = blockIdx.x >> 7;
    int d = dblk * 256 + tid;
    float Adn[NS], ap[NS], h[NS];
    #pragma unroll
    for (int j = 0; j < 4; ++j)
        *(float4*)&Adn[j * 4] = ((const float4*)(logA + (size_t)d * NS))[j];
    #pragma unroll
    for (int n = 0; n < NS; ++n) { Adn[n] = -__expf(Adn[n]); ap[n] = 1.f; h[n] = 0.f; }
    const u16* dtp = dt + ((size_t)b * T_SEQ + c * CL) * DI + d;
    const u16* xfp = xf + ((size_t)b * T_SEQ + c * CL) * DI + d;
    const float* Bp = Bt + ((size_t)b * T_SEQ + c * CL) * NS;
    #pragma unroll 8
    for (int i = 0; i < CL; ++i) {
        float dtv = b2f(dtp[(size_t)i * DI]);
        float xv  = b2f(xfp[(size_t)i * DI]);
        float ux = dtv * xv;
        float Bv[NS];
        #pragma unroll
        for (int j = 0; j < 4; ++j) *(float4*)&Bv[j * 4] = ((const float4*)(Bp + (size_t)i * NS))[j];
        #pragma unroll
        for (int n = 0; n < NS; ++n) {
            float dA = __expf(Adn[n] * dtv);
            h[n] = fmaf(dA, h[n], ux * Bv[n]);
            ap[n] *= dA;
        }
    }
    size_t o = ((((size_t)c * 2 + b) * DI) + d) * NS;   // layout [c][b][d][n]
    #pragma unroll
    for (int j = 0; j < 4; ++j) {
        ((float4*)(Aprod + o))[j] = *(float4*)&ap[j * 4];
        ((float4*)(S + o))[j]     = *(float4*)&h[j * 4];
    }
}

__global__ __launch_bounds__(256) void scanB(const float* __restrict__ Aprod, const float* __restrict__ S,
                                             float* __restrict__ Hin) {
    int chain = blockIdx.x * 256 + threadIdx.x;   // 32768 = B*DI*NS
    float h = 0.f;
    #pragma unroll 8
    for (int c = 0; c < NC; ++c) {
        size_t o = (size_t)c * 32768 + chain;
        Hin[o] = h;
        h = fmaf(Aprod[o], h, S[o]);
    }
}

__global__ __launch_bounds__(256) void scanC(const u16* __restrict__ dt, const u16* __restrict__ xf,
                                             const float* __restrict__ Bt, const float* __restrict__ Ct,
                                             const float* __restrict__ logA, const float* __restrict__ Hin,
                                             const u16* __restrict__ xz, u16* __restrict__ ym) {
    int tid = threadIdx.x;
    int dblk = blockIdx.x & 3;
    int c = (blockIdx.x >> 2) & (NC - 1);
    int b = blockIdx.x >> 7;
    int d = dblk * 256 + tid;
    float Adn[NS], h[NS];
    #pragma unroll
    for (int j = 0; j < 4; ++j)
        *(float4*)&Adn[j * 4] = ((const float4*)(logA + (size_t)d * NS))[j];
    #pragma unroll
    for (int n = 0; n < NS; ++n) Adn[n] = -__expf(Adn[n]);
    size_t o = ((((size_t)c * 2 + b) * DI) + d) * NS;
    #pragma unroll
    for (int j = 0; j < 4; ++j) *(float4*)&h[j * 4] = ((const float4*)(Hin + o))[j];
    const u16* dtp = dt + ((size_t)b * T_SEQ + c * CL) * DI + d;
    const u16* xfp = xf + ((size_t)b * T_SEQ + c * CL) * DI + d;
    const float* Bp = Bt + ((size_t)b * T_SEQ + c * CL) * NS;
    const float* Cp = Ct + ((size_t)b * T_SEQ + c * CL) * NS;
    const u16* zp = xz + ((size_t)b * T_SEQ + c * CL) * 2048 + 1024 + d;
    u16* yp = ym + ((size_t)b * T_SEQ + c * CL) * DI + d;
    #pragma unroll 8
    for (int i = 0; i < CL; ++i) {
        float dtv = b2f(dtp[(size_t)i * DI]);
        float xv  = b2f(xfp[(size_t)i * DI]);
        float ux = dtv * xv;
        float Bv[NS], Cv[NS];
        #pragma unroll
        for (int j = 0; j < 4; ++j) {
            *(float4*)&Bv[j * 4] = ((const float4*)(Bp + (size_t)i * NS))[j];
            *(float4*)&Cv[j * 4] = ((const float4*)(Cp + (size_t)i * NS))[j];
        }
        float r = 0.f;
        #pragma unroll
        for (int n = 0; n < NS; ++n) {
            float dA = __expf(Adn[n] * dtv);
            h[n] = fmaf(dA, h[n], ux * Bv[n]);
            r = fmaf(h[n], Cv[n], r);
        }
        float zv = b2f(zp[(size_t)i * 2048]);
        float sz = zv / (1.f + __expf(-zv));
        yp[(size_t)i * DI] = f2b(r * sz);
    }
}

// ---------------- launch ----------------
extern "C" void kernel_launch(void* const* d_in, const int* in_sizes, int n_in,
                              void* d_out, int out_size, void* d_ws, size_t ws_size,
                              hipStream_t stream) {
    const float* x     = (const float*)d_in[0];
    const float* ln_g  = (const float*)d_in[1];
    const float* ln_b  = (const float*)d_in[2];
    const float* W_in  = (const float*)d_in[3];
    const float* conv_w= (const float*)d_in[4];
    const float* conv_b= (const float*)d_in[5];
    const float* W_B   = (const float*)d_in[6];
    const float* W_C   = (const float*)d_in[7];
    const float* W_dt  = (const float*)d_in[8];
    const float* b_dt  = (const float*)d_in[9];
    const float* log_A = (const float*)d_in[10];
    const float* W_out = (const float*)d_in[11];

    char* ws = (char*)d_ws;
    u16* wInB  = (u16*)(ws + 0);          // 2 MB
    u16* wCat  = (u16*)(ws + 2097152);    // 1088x1024 bf16 = 2.125 MB
    u16* wOutB = (u16*)(ws + 4325376);    // 1 MB
    u16* xnB   = (u16*)(ws + 5373952);    // 2 MB
    u16* xzB   = (u16*)(ws + 7471104);    // 8 MB
    u16* xfB   = (u16*)(ws + 15859712);   // 4 MB
    u16* dtB   = (u16*)(ws + 20054016);   // 4 MB
    float* BtF = (float*)(ws + 24248320); // 128 KB
    float* CtF = (float*)(ws + 24379392); // 128 KB
    u16* ymB   = (u16*)(ws + 24510464);   // 4 MB
    float* ApF = (float*)(ws + 28704768); // 4 MB (reused as gemm2 partial p0)
    float* SF  = (float*)(ws + 32899072); // 4 MB (p1)
    float* HiF = (float*)(ws + 37093376); // 4 MB (end ~41.3 MB)

    prep_k<<<4672, 256, 0, stream>>>(W_in, W_dt, W_out, W_B, W_C, wInB, wCat, wOutB,
                                     x, ln_g, ln_b, xnB);
    gemm128<16, 0><<<512, 256, 0, stream>>>(16, xnB, 512, wInB, 512,
            (void*)xzB, 2048, nullptr, nullptr, nullptr);
    conv_k<<<2048, 256, 0, stream>>>(xzB, conv_w, conv_b, xfB);
    gemm128<32, 4><<<272, 256, 0, stream>>>(16, xfB, 1024, wCat, 1024,
            (void*)dtB, 1024, b_dt, BtF, CtF);
    scanA<<<256, 256, 0, stream>>>(dtB, xfB, BtF, log_A, ApF, SF);
    scanB<<<128, 256, 0, stream>>>(ApF, SF, HiF);
    scanC<<<256, 256, 0, stream>>>(dtB, xfB, BtF, CtF, log_A, HiF, xzB, ymB);
    gemm2_k<<<512, 512, 0, stream>>>(ymB, wOutB, ApF, SF);
    merge_k<<<1024, 256, 0, stream>>>(ApF, SF, x, (float*)d_out);
}

// Round 18
// 110.566 us; speedup vs baseline: 1.1275x; 1.1275x over previous
//
#include <hip/hip_runtime.h>

#define T_SEQ 1024
#define DM 512
#define DI 1024
#define NS 16
#define NC 32      // scan chunks
#define CL 32      // chunk length (NC*CL == T_SEQ)

typedef __attribute__((ext_vector_type(8))) short short8;
typedef __attribute__((ext_vector_type(4))) float f32x4;
typedef unsigned short u16;
typedef unsigned int u32;

__device__ inline float b2f(u16 u) {
    unsigned v = ((unsigned)u) << 16;
    return __builtin_bit_cast(float, v);
}
__device__ inline u16 f2b(float f) {
    unsigned u = __builtin_bit_cast(unsigned, f);
    u += 0x7fff + ((u >> 16) & 1);   // RNE
    return (u16)(u >> 16);
}

// async global -> LDS, 16B/lane: per-lane global src, wave-uniform LDS base (+lane*16 by HW)
__device__ inline void g2l16(const u16* g, const short* l) {
    __builtin_amdgcn_global_load_lds((const __attribute__((address_space(1))) u32*)g,
                                     (__attribute__((address_space(3))) u32*)l, 16, 0, 0);
}

template<int K> __device__ __forceinline__ void vmwait() {
    if constexpr (K == 0) asm volatile("s_waitcnt vmcnt(0)" ::: "memory");
    else if constexpr (K == 2) asm volatile("s_waitcnt vmcnt(2)" ::: "memory");
}

// ---------------- prep: cast weights + build wCat (1088x1024) + LayerNorm ----------------
// wCat rows: [0,1024)=W_dt, [1024,1040)=W_B, [1040,1056)=W_C, [1056,1088)=zeros
__global__ __launch_bounds__(256) void prep_k(const float* __restrict__ Win, const float* __restrict__ Wdt,
                       const float* __restrict__ Wout, const float* __restrict__ Wb,
                       const float* __restrict__ Wc,
                       u16* __restrict__ oWin, u16* __restrict__ wCat, u16* __restrict__ oWout,
                       const float* __restrict__ x, const float* __restrict__ g,
                       const float* __restrict__ be, u16* __restrict__ xn) {
    if (blockIdx.x < 2624) {
        int i = blockIdx.x * 256 + threadIdx.x;     // float4 index
        const float* s; u16* d; int off;
        if (i < 262144)      { s = Win;  d = oWin;  off = i; }
        else if (i < 524288) { s = Wdt;  d = wCat;  off = i - 262144; }
        else if (i < 655360) { s = Wout; d = oWout; off = i - 524288; }
        else if (i < 659456) { s = Wb;   d = wCat + 1048576; off = i - 655360; }
        else if (i < 663552) { s = Wc;   d = wCat + 1064960; off = i - 659456; }
        else {  // zero pad rows 1056..1087
            u16* dz = wCat + 1081344 + (i - 663552) * 4;
            dz[0] = 0; dz[1] = 0; dz[2] = 0; dz[3] = 0;
            return;
        }
        float4 v = ((const float4*)s)[off];
        d[off * 4 + 0] = f2b(v.x);
        d[off * 4 + 1] = f2b(v.y);
        d[off * 4 + 2] = f2b(v.z);
        d[off * 4 + 3] = f2b(v.w);
        return;
    }
    int row = blockIdx.x - 2624, tid = threadIdx.x;
    float2 v = ((const float2*)(x + row * DM))[tid];
    float s = v.x + v.y, q = v.x * v.x + v.y * v.y;
    #pragma unroll
    for (int m = 1; m < 64; m <<= 1) { s += __shfl_xor(s, m); q += __shfl_xor(q, m); }
    __shared__ float ss[4], qq[4];
    if ((tid & 63) == 0) { ss[tid >> 6] = s; qq[tid >> 6] = q; }
    __syncthreads();
    s = ss[0] + ss[1] + ss[2] + ss[3];
    q = qq[0] + qq[1] + qq[2] + qq[3];
    float mu = s / DM;
    float var = q / DM - mu * mu;
    float rs = rsqrtf(var + 1e-5f);
    int c = tid * 2;
    xn[row * DM + c]     = f2b((v.x - mu) * rs * g[c] + be[c]);
    xn[row * DM + c + 1] = f2b((v.y - mu) * rs * g[c + 1] + be[c + 1]);
}

// ---------------- bf16 GEMM core: 64x64 tile, BK=64, 8 WAVES (512 thr) — r13 proven ----------------
// Waves 2(row)x4(col), each 32(M)x16(N): MI=2, NJ=1. Ring-3 LDS (48KB -> 3 blocks/CU,
// 24 waves/CU), depth-2 prefetch, counted vmcnt(2), ONE barrier per phase, setprio on MFMA.
// XOR swizzle chunk^=(row&7) source-side + read-side.
// EPI 0: bf16  EPI 2: acc+resid->f32  EPI 3: raw f32
// EPI 4: cols<1024 softplus->bf16, 1024-1039->Bt f32, 1040-1055->Ct f32, else drop
template<int NT, int EPI>
__device__ __forceinline__ void gemm_core64(int bx, int by,
        const u16* __restrict__ A, int lda, const u16* __restrict__ Bw, int ldb,
        void* __restrict__ outp, int ldo, const float* __restrict__ extra,
        float* __restrict__ BtF, float* __restrict__ CtF) {
    __shared__ short a_sh[3 * 4096];        // 3 stages x 64x64
    __shared__ short b_sh[3 * 4096];
    int tid = threadIdx.x, w = tid >> 6, lane = tid & 63;
    int m0 = bx * 64, n0 = by * 64;
    int wr = (w >> 2) * 32, wc = (w & 3) * 16;
    int lr = lane & 15, kg = lane >> 4;
    f32x4 acc[2] = {};
    const u16* Abase = A + (size_t)m0 * lda;
    const u16* Bbase = Bw + (size_t)n0 * ldb;
    int lrow = lane >> 3;                   // 0..7
    int cl = lane & 7;                      // 16B chunk within 128B row
    int row1 = w * 8 + lrow;                // 0..63
    int sc = cl ^ (row1 & 7);               // pre-swizzled source chunk (involution)

    auto stage = [&](int buf, int kt) {
        int k0 = kt * 64;
        g2l16(Abase + (size_t)row1 * lda + k0 + sc * 8, a_sh + buf * 4096 + w * 512);
        g2l16(Bbase + (size_t)row1 * ldb + k0 + sc * 8, b_sh + buf * 4096 + w * 512);
    };

    stage(0, 0);
    stage(1, 1);
    for (int t = 0; t < NT; ++t) {
        if (t + 1 < NT) vmwait<2>();        // tile t landed; t+1 stays in flight
        else vmwait<0>();
        __builtin_amdgcn_s_barrier();       // all waves' tile-t DMAs done; buf[(t-1)%3] reads done
        if (t + 2 < NT) stage((t + 2) % 3, t + 2);
        const short* as = a_sh + (t % 3) * 4096;
        const short* bs = b_sh + (t % 3) * 4096;
        int rsw = lr & 7;
        __builtin_amdgcn_s_setprio(1);
        #pragma unroll
        for (int kk = 0; kk < 2; ++kk) {
            short8 af[2], bfr;
            #pragma unroll
            for (int i = 0; i < 2; ++i) {
                int row = wr + i * 16 + lr;
                af[i] = *(const short8*)&as[row * 64 + ((kk * 4 + kg) ^ rsw) * 8];
            }
            {
                int row = wc + lr;
                bfr = *(const short8*)&bs[row * 64 + ((kk * 4 + kg) ^ rsw) * 8];
            }
            #pragma unroll
            for (int i = 0; i < 2; ++i)
                acc[i] = __builtin_amdgcn_mfma_f32_16x16x32_bf16(af[i], bfr, acc[i], 0, 0, 0);
        }
        __builtin_amdgcn_s_setprio(0);
    }

    int rb = (lane >> 4) * 4, cc = lane & 15;
    #pragma unroll
    for (int i = 0; i < 2; ++i) {
        #pragma unroll
        for (int r = 0; r < 4; ++r) {
            int row = m0 + wr + i * 16 + rb + r;
            int col = n0 + wc + cc;
            float v = acc[i][r];
            if (EPI == 0) {
                ((u16*)outp)[(size_t)row * ldo + col] = f2b(v);
            } else if (EPI == 2) {
                ((float*)outp)[(size_t)row * ldo + col] = v + extra[(size_t)row * ldo + col];
            } else if (EPI == 3) {
                ((float*)outp)[(size_t)row * ldo + col] = v;
            } else {   // EPI 4: dt | Bt | Ct | drop
                if (col < 1024) {
                    float xx = v + extra[col];
                    float sp = (xx > 20.f) ? xx : log1pf(__expf(xx));
                    ((u16*)outp)[(size_t)row * ldo + col] = f2b(sp);
                } else if (col < 1040) {
                    BtF[(size_t)row * NS + (col - 1024)] = v;
                } else if (col < 1056) {
                    CtF[(size_t)row * NS + (col - 1040)] = v;
                }
            }
        }
    }
}

template<int NT, int EPI>
__global__ __launch_bounds__(512) void gemm8(int gx,
                                             const u16* __restrict__ A, int lda,
                                             const u16* __restrict__ Bw, int ldb,
                                             void* __restrict__ outp, int ldo,
                                             const float* __restrict__ extra,
                                             float* __restrict__ BtF, float* __restrict__ CtF) {
    int bx = blockIdx.x % gx, by = blockIdx.x / gx;
    gemm_core64<NT, EPI>(bx, by, A, lda, Bw, ldb, outp, ldo, extra, BtF, CtF);
}

// gemm2 split-K2: 512 blocks = 2 k-halves x (32 m x 8 n); f32 partials
__global__ __launch_bounds__(512) void gemm2_k(const u16* __restrict__ ym, const u16* __restrict__ Wout,
                                               float* __restrict__ p0, float* __restrict__ p1) {
    int bid = blockIdx.x;
    int ks = bid >> 8, rem = bid & 255;
    int bx = rem & 31, by = rem >> 5;
    float* p = ks ? p1 : p0;
    gemm_core64<8, 3>(bx, by, ym + ks * 512, DI, Wout + ks * 512, DI,
                      (void*)p, DM, nullptr, nullptr, nullptr);
}

// merge split-K partials + residual -> f32 out
__global__ __launch_bounds__(256) void merge_k(const float* __restrict__ p0, const float* __restrict__ p1,
                                               const float* __restrict__ x, float* __restrict__ out) {
    int i = blockIdx.x * 256 + threadIdx.x;   // float4 index, 262144 total
    float4 a = ((const float4*)p0)[i];
    float4 b = ((const float4*)p1)[i];
    float4 e = ((const float4*)x)[i];
    float4 o;
    o.x = a.x + b.x + e.x;
    o.y = a.y + b.y + e.y;
    o.z = a.z + b.z + e.z;
    o.w = a.w + b.w + e.w;
    ((float4*)out)[i] = o;
}

// ---------------- depthwise causal conv(k=4) + SiLU: 4 elems/thread, 2048 blocks ----------------
__global__ __launch_bounds__(256) void conv_k(const u16* __restrict__ xz, const float* __restrict__ w,
                                              const float* __restrict__ cb, u16* __restrict__ xf) {
    int base = (blockIdx.x * 256 + threadIdx.x) * 4;   // = (b*T + t)*DI + d0, d0 % 4 == 0
    int d0 = base & (DI - 1);
    int bt = base >> 10;
    int t = bt & (T_SEQ - 1);
    float4 cbv = *(const float4*)(cb + d0);
    float s0 = cbv.x, s1 = cbv.y, s2 = cbv.z, s3 = cbv.w;
    float4 w0 = *(const float4*)(w + (d0 + 0) * 4);
    float4 w1 = *(const float4*)(w + (d0 + 1) * 4);
    float4 w2 = *(const float4*)(w + (d0 + 2) * 4);
    float4 w3 = *(const float4*)(w + (d0 + 3) * 4);
    const float* pw0 = (const float*)&w0;
    const float* pw1 = (const float*)&w1;
    const float* pw2 = (const float*)&w2;
    const float* pw3 = (const float*)&w3;
    #pragma unroll
    for (int i = 0; i < 4; ++i) {
        int tt = t - 3 + i;
        if (tt >= 0) {
            ushort4 xv = *(const ushort4*)(xz + (size_t)(bt - 3 + i) * 2048 + d0);
            s0 += pw0[i] * b2f(xv.x);
            s1 += pw1[i] * b2f(xv.y);
            s2 += pw2[i] * b2f(xv.z);
            s3 += pw3[i] * b2f(xv.w);
        }
    }
    ushort4 o;
    o.x = f2b(s0 / (1.f + __expf(-s0)));
    o.y = f2b(s1 / (1.f + __expf(-s1)));
    o.z = f2b(s2 / (1.f + __expf(-s2)));
    o.w = f2b(s3 / (1.f + __expf(-s3)));
    *(ushort4*)(xf + base) = o;
}

// ---------------- chunked selective scan (CL=32, NC=32) — three separate kernels (r13 proven) ----------------
__global__ __launch_bounds__(256) void scanA(const u16* __restrict__ dt, const u16* __restrict__ xf,
                                             const float* __restrict__ Bt, const float* __restrict__ logA,
                                             float* __restrict__ Aprod, float* __restrict__ S) {
    int tid = threadIdx.x;
    int dblk = blockIdx.x & 3;          // DI/256
    int c = (blockIdx.x >> 2) & (NC - 1);
    int b = blockIdx.x >> 7;
    int d = dblk * 256 + tid;
    float Adn[NS], ap[NS], h[NS];
    #pragma unroll
    for (int j = 0; j < 4; ++j)
        *(float4*)&Adn[j * 4] = ((const float4*)(logA + (size_t)d * NS))[j];
    #pragma unroll
    for (int n = 0; n < NS; ++n) { Adn[n] = -__expf(Adn[n]); ap[n] = 1.f; h[n] = 0.f; }
    const u16* dtp = dt + ((size_t)b * T_SEQ + c * CL) * DI + d;
    const u16* xfp = xf + ((size_t)b * T_SEQ + c * CL) * DI + d;
    const float* Bp = Bt + ((size_t)b * T_SEQ + c * CL) * NS;
    #pragma unroll 8
    for (int i = 0; i < CL; ++i) {
        float dtv = b2f(dtp[(size_t)i * DI]);
        float xv  = b2f(xfp[(size_t)i * DI]);
        float ux = dtv * xv;
        float Bv[NS];
        #pragma unroll
        for (int j = 0; j < 4; ++j) *(float4*)&Bv[j * 4] = ((const float4*)(Bp + (size_t)i * NS))[j];
        #pragma unroll
        for (int n = 0; n < NS; ++n) {
            float dA = __expf(Adn[n] * dtv);
            h[n] = fmaf(dA, h[n], ux * Bv[n]);
            ap[n] *= dA;
        }
    }
    size_t o = ((((size_t)c * 2 + b) * DI) + d) * NS;   // layout [c][b][d][n]
    #pragma unroll
    for (int j = 0; j < 4; ++j) {
        ((float4*)(Aprod + o))[j] = *(float4*)&ap[j * 4];
        ((float4*)(S + o))[j]     = *(float4*)&h[j * 4];
    }
}

__global__ __launch_bounds__(256) void scanB(const float* __restrict__ Aprod, const float* __restrict__ S,
                                             float* __restrict__ Hin) {
    int chain = blockIdx.x * 256 + threadIdx.x;   // 32768 = B*DI*NS
    float h = 0.f;
    #pragma unroll 8
    for (int c = 0; c < NC; ++c) {
        size_t o = (size_t)c * 32768 + chain;
        Hin[o] = h;
        h = fmaf(Aprod[o], h, S[o]);
    }
}

__global__ __launch_bounds__(256) void scanC(const u16* __restrict__ dt, const u16* __restrict__ xf,
                                             const float* __restrict__ Bt, const float* __restrict__ Ct,
                                             const float* __restrict__ logA, const float* __restrict__ Hin,
                                             const u16* __restrict__ xz, u16* __restrict__ ym) {
    int tid = threadIdx.x;
    int dblk = blockIdx.x & 3;
    int c = (blockIdx.x >> 2) & (NC - 1);
    int b = blockIdx.x >> 7;
    int d = dblk * 256 + tid;
    float Adn[NS], h[NS];
    #pragma unroll
    for (int j = 0; j < 4; ++j)
        *(float4*)&Adn[j * 4] = ((const float4*)(logA + (size_t)d * NS))[j];
    #pragma unroll
    for (int n = 0; n < NS; ++n) Adn[n] = -__expf(Adn[n]);
    size_t o = ((((size_t)c * 2 + b) * DI) + d) * NS;
    #pragma unroll
    for (int j = 0; j < 4; ++j) *(float4*)&h[j * 4] = ((const float4*)(Hin + o))[j];
    const u16* dtp = dt + ((size_t)b * T_SEQ + c * CL) * DI + d;
    const u16* xfp = xf + ((size_t)b * T_SEQ + c * CL) * DI + d;
    const float* Bp = Bt + ((size_t)b * T_SEQ + c * CL) * NS;
    const float* Cp = Ct + ((size_t)b * T_SEQ + c * CL) * NS;
    const u16* zp = xz + ((size_t)b * T_SEQ + c * CL) * 2048 + 1024 + d;
    u16* yp = ym + ((size_t)b * T_SEQ + c * CL) * DI + d;
    #pragma unroll 8
    for (int i = 0; i < CL; ++i) {
        float dtv = b2f(dtp[(size_t)i * DI]);
        float xv  = b2f(xfp[(size_t)i * DI]);
        float ux = dtv * xv;
        float Bv[NS], Cv[NS];
        #pragma unroll
        for (int j = 0; j < 4; ++j) {
            *(float4*)&Bv[j * 4] = ((const float4*)(Bp + (size_t)i * NS))[j];
            *(float4*)&Cv[j * 4] = ((const float4*)(Cp + (size_t)i * NS))[j];
        }
        float r = 0.f;
        #pragma unroll
        for (int n = 0; n < NS; ++n) {
            float dA = __expf(Adn[n] * dtv);
            h[n] = fmaf(dA, h[n], ux * Bv[n]);
            r = fmaf(h[n], Cv[n], r);
        }
        float zv = b2f(zp[(size_t)i * 2048]);
        float sz = zv / (1.f + __expf(-zv));
        yp[(size_t)i * DI] = f2b(r * sz);
    }
}

// ---------------- launch ----------------
extern "C" void kernel_launch(void* const* d_in, const int* in_sizes, int n_in,
                              void* d_out, int out_size, void* d_ws, size_t ws_size,
                              hipStream_t stream) {
    const float* x     = (const float*)d_in[0];
    const float* ln_g  = (const float*)d_in[1];
    const float* ln_b  = (const float*)d_in[2];
    const float* W_in  = (const float*)d_in[3];
    const float* conv_w= (const float*)d_in[4];
    const float* conv_b= (const float*)d_in[5];
    const float* W_B   = (const float*)d_in[6];
    const float* W_C   = (const float*)d_in[7];
    const float* W_dt  = (const float*)d_in[8];
    const float* b_dt  = (const float*)d_in[9];
    const float* log_A = (const float*)d_in[10];
    const float* W_out = (const float*)d_in[11];

    char* ws = (char*)d_ws;
    u16* wInB  = (u16*)(ws + 0);          // 2 MB
    u16* wCat  = (u16*)(ws + 2097152);    // 1088x1024 bf16 = 2.125 MB
    u16* wOutB = (u16*)(ws + 4325376);    // 1 MB
    u16* xnB   = (u16*)(ws + 5373952);    // 2 MB
    u16* xzB   = (u16*)(ws + 7471104);    // 8 MB
    u16* xfB   = (u16*)(ws + 15859712);   // 4 MB
    u16* dtB   = (u16*)(ws + 20054016);   // 4 MB
    float* BtF = (float*)(ws + 24248320); // 128 KB
    float* CtF = (float*)(ws + 24379392); // 128 KB
    u16* ymB   = (u16*)(ws + 24510464);   // 4 MB
    float* ApF = (float*)(ws + 28704768); // 4 MB (reused as gemm2 partial p0)
    float* SF  = (float*)(ws + 32899072); // 4 MB (p1)
    float* HiF = (float*)(ws + 37093376); // 4 MB (end ~41.3 MB)

    prep_k<<<4672, 256, 0, stream>>>(W_in, W_dt, W_out, W_B, W_C, wInB, wCat, wOutB,
                                     x, ln_g, ln_b, xnB);
    gemm8<8, 0><<<1024, 512, 0, stream>>>(32, xnB, 512, wInB, 512,
            (void*)xzB, 2048, nullptr, nullptr, nullptr);
    conv_k<<<2048, 256, 0, stream>>>(xzB, conv_w, conv_b, xfB);
    gemm8<16, 4><<<544, 512, 0, stream>>>(32, xfB, 1024, wCat, 1024,
            (void*)dtB, 1024, b_dt, BtF, CtF);
    scanA<<<256, 256, 0, stream>>>(dtB, xfB, BtF, log_A, ApF, SF);
    scanB<<<128, 256, 0, stream>>>(ApF, SF, HiF);
    scanC<<<256, 256, 0, stream>>>(dtB, xfB, BtF, CtF, log_A, HiF, xzB, ymB);
    gemm2_k<<<512, 512, 0, stream>>>(ymB, wOutB, ApF, SF);
    merge_k<<<1024, 256, 0, stream>>>(ApF, SF, x, (float*)d_out);
}